// Round 9
// baseline (173.944 us; speedup 1.0000x reference)
//
#include <hip/hip_runtime.h>
#include <cstdint>

#define N_NODES 100000
#define N_EDGES 3200000
#define SPAN    256                              // nodes per bucket
#define SHIFT   8
#define NB      ((N_NODES + SPAN - 1) / SPAN)    // 391 buckets
#define CHUNK   4096                             // edges per bin block
#define BTH     512
#define NITER   (CHUNK / BTH)                    // 8
#define NBLK    ((N_EDGES + CHUNK - 1) / CHUNK)  // 782 blocks
#define PREF_W  (NB + 1)                         // 392

// ---------------------------------------------------------------------------
// Kernel 1: per-node prep. Inline mask-dtype detect; u = vm*e^{i va};
// base = (pg-pd, qg-qd); zero d_out.
// ---------------------------------------------------------------------------
__global__ __launch_bounds__(256)
void prep_kernel(const float* __restrict__ pred,
                 const float* __restrict__ target,
                 const void* __restrict__ mask,
                 float2* __restrict__ u_tab,
                 float2* __restrict__ base_pq,
                 float* __restrict__ d_out, int out_size) {
    __shared__ int s_mask8;
    if (threadIdx.x < 64) {
        uint32_t w = ((const uint32_t*)mask)[threadIdx.x];
        bool nz = (w & 0xFFFFFF00u) != 0u;           // any off-aligned byte set
        unsigned long long m = __ballot(nz);
        if (threadIdx.x == 0) s_mask8 = (m != 0ull) ? 1 : 0;
    }
    if (blockIdx.x == 0 && threadIdx.x == 0)
        for (int k = 0; k < out_size; ++k) d_out[k] = 0.0f;
    __syncthreads();

    int i = blockIdx.x * 256 + threadIdx.x;
    if (i >= N_NODES) return;

    const float2* p2 = (const float2*)pred;
    const float2* t2 = (const float2*)target;
    float2 pa = p2[3 * i], pb = p2[3 * i + 1], pc = p2[3 * i + 2];
    float2 ta = t2[3 * i], tb = t2[3 * i + 1], tc = t2[3 * i + 2];
    float pr[6] = {pa.x, pa.y, pb.x, pb.y, pc.x, pc.y};
    float tg[6] = {ta.x, ta.y, tb.x, tb.y, tc.x, tc.y};
    int mk[6];
    if (s_mask8) {   // 1-byte bool
        const uint16_t* mu = (const uint16_t*)mask;
        uint16_t m0 = mu[3 * i], m1 = mu[3 * i + 1], m2 = mu[3 * i + 2];
        mk[0] = m0 & 0xFF; mk[1] = m0 >> 8;
        mk[2] = m1 & 0xFF; mk[3] = m1 >> 8;
        mk[4] = m2 & 0xFF; mk[5] = m2 >> 8;
    } else {         // int32
        const int2* mi = (const int2*)mask;
        int2 m0 = mi[3 * i], m1 = mi[3 * i + 1], m2 = mi[3 * i + 2];
        mk[0] = m0.x; mk[1] = m0.y; mk[2] = m1.x;
        mk[3] = m1.y; mk[4] = m2.x; mk[5] = m2.y;
    }
    float tp[6];
    #pragma unroll
    for (int j = 0; j < 6; ++j) tp[j] = mk[j] ? pr[j] : tg[j];

    float s, c;
    sincosf(tp[1], &s, &c);
    u_tab[i]   = make_float2(tp[0] * c, tp[0] * s);
    base_pq[i] = make_float2(tp[2] - tp[4], tp[3] - tp[5]);
}

// ---------------------------------------------------------------------------
// Kernel 2: bin. Per 4096-edge block: histogram -> shfl scan -> LDS counting
// sort -> STREAMING arena write (deterministic, zero global atomics) +
// TRANSPOSED u16 prefix write (pref_T[b][t], coalesced consumer reads).
// Record: rc.x = vr with low 8 mantissa bits = lid; rc.y = vi (exact).
// ---------------------------------------------------------------------------
__global__ __launch_bounds__(BTH)
void bin_kernel(const void* __restrict__ edge_index,
                const float2* __restrict__ edge_attr,
                const float2* __restrict__ u_tab,
                uint2* __restrict__ recs,           // [NBLK][CHUNK]
                uint16_t* __restrict__ pref_T) {    // [PREF_W][NBLK]
    __shared__ uint2 s_rec[CHUNK];         // 32 KB
    __shared__ uint32_t s_cnt[NB];         // counts, then running ranks
    __shared__ uint32_t s_pref[PREF_W];    // exclusive prefix
    __shared__ uint32_t s_wsum[8], s_woff[8];
    __shared__ int s_i64;

    const int tid = threadIdx.x;
    const int lane = tid & 63, wid = tid >> 6;
    if (tid < 64) {
        uint32_t w = ((const uint32_t*)edge_index)[tid];
        bool nz = (tid & 1) && (w != 0u);  // odd word nonzero -> int32
        unsigned long long m = __ballot(nz);
        if (tid == 0) s_i64 = (m == 0ull) ? 1 : 0;
    }
    if (tid < NB) s_cnt[tid] = 0u;
    __syncthreads();
    const bool is64 = (s_i64 != 0);
    const int ebase = blockIdx.x * CHUNK;
    const int nE = min(CHUNK, N_EDGES - ebase);

    // pass 1: histogram, cache src ids in registers
    uint32_t src_r[NITER];
    #pragma unroll
    for (int it = 0; it < NITER; ++it) {
        int j = it * BTH + tid;
        uint32_t s = 0u;
        if (j < nE) {
            int e = ebase + j;
            s = is64 ? (uint32_t)((const unsigned long long*)edge_index)[e]
                     : ((const uint32_t*)edge_index)[e];
            atomicAdd(&s_cnt[s >> SHIFT], 1u);
        }
        src_r[it] = s;
    }
    __syncthreads();

    // two-level shfl scan over 512 slots (NB=391 live)
    {
        uint32_t v0 = (tid < NB) ? s_cnt[tid] : 0u;
        uint32_t x = v0;
        #pragma unroll
        for (int off = 1; off < 64; off <<= 1) {
            uint32_t y = (uint32_t)__shfl_up((int)x, off, 64);
            if (lane >= off) x += y;
        }
        if (lane == 63) s_wsum[wid] = x;
        __syncthreads();
        if (tid < 8) {
            uint32_t w0 = s_wsum[tid];
            uint32_t xx = w0;
            #pragma unroll
            for (int off = 1; off < 8; off <<= 1) {
                uint32_t y = (uint32_t)__shfl_up((int)xx, off, 64);
                if (tid >= off) xx += y;
            }
            s_woff[tid] = xx - w0;         // exclusive wave offset
        }
        __syncthreads();
        uint32_t incl = x + s_woff[wid];
        if (tid < NB) s_pref[tid + 1] = incl;
        if (tid == 0) s_pref[0] = 0u;
        if (tid < NB) s_cnt[tid] = 0u;     // reuse as running rank
        __syncthreads();
    }

    // pass 2: compute record, place bucket-sorted in LDS
    #pragma unroll
    for (int it = 0; it < NITER; ++it) {
        int j = it * BTH + tid;
        if (j < nE) {
            int e = ebase + j;
            uint32_t dst = is64
                ? (uint32_t)((const unsigned long long*)edge_index)[(size_t)N_EDGES + e]
                : ((const uint32_t*)edge_index)[(size_t)N_EDGES + e];
            float2 gb = edge_attr[e];
            float2 u  = u_tab[dst];
            float vr = gb.x * u.x - gb.y * u.y;        // Re[(g-ib)conj(u)]
            float vi = -(gb.y * u.x + gb.x * u.y);     // Im[(g-ib)conj(u)]
            uint32_t nid = src_r[it];
            uint32_t bk = nid >> SHIFT, lid = nid & (SPAN - 1);
            uint32_t r = atomicAdd(&s_cnt[bk], 1u);    // intra-block rank
            uint2 rc;
            rc.x = (__float_as_uint(vr) & ~0xFFu) | lid;    // lid: 8 bits
            rc.y = __float_as_uint(vi);                     // exact
            s_rec[s_pref[bk] + r] = rc;
        }
    }
    __syncthreads();

    // streaming arena write: fully coalesced uint4 copy
    {
        const uint4* s4 = (const uint4*)s_rec;
        uint4* a4 = (uint4*)(recs + (size_t)blockIdx.x * CHUNK);
        for (int k = tid; k < nE / 2; k += BTH) a4[k] = s4[k];
        if ((nE & 1) && tid == 0)
            recs[(size_t)blockIdx.x * CHUNK + nE - 1] = s_rec[nE - 1];
    }
    // transposed u16 prefix write (scattered 2B stores, fire-and-forget;
    // makes the reduce-side read a single coalesced run per column)
    for (int b = tid; b < PREF_W; b += BTH)
        pref_T[(size_t)b * NBLK + blockIdx.x] = (uint16_t)s_pref[b];
}

// ---------------------------------------------------------------------------
// Kernel 3: reduce. One 1024-thread block per bucket b: thread t processes
// producer-block t's run [pref_T[b][t], pref_T[b+1][t]) — coalesced prefix
// loads, 2x-unrolled record loads (MLP), LDS f32 accumulate (4 replicas).
// ---------------------------------------------------------------------------
__global__ __launch_bounds__(1024)
void reduce_kernel(const uint2* __restrict__ recs,
                   const uint16_t* __restrict__ pref_T,
                   const float2* __restrict__ u_tab,
                   const float2* __restrict__ base_pq,
                   float* __restrict__ d_out) {
    __shared__ float2 s_acc[4][SPAN];      // 8 KB
    __shared__ float s_part[16];
    if (threadIdx.x < SPAN) {
        #pragma unroll
        for (int r = 0; r < 4; ++r) s_acc[r][threadIdx.x] = make_float2(0.0f, 0.0f);
    }
    __syncthreads();

    const int b = blockIdx.x;
    const int rep = (threadIdx.x >> 6) & 3;
    if (threadIdx.x < NBLK) {
        uint32_t s = pref_T[(size_t)b * NBLK + threadIdx.x];
        uint32_t e = pref_T[(size_t)(b + 1) * NBLK + threadIdx.x];
        const uint2* arena = recs + (size_t)threadIdx.x * CHUNK;
        uint32_t j = s;
        for (; j + 2 <= e; j += 2) {       // 2x unroll: both loads in flight
            uint2 r0 = arena[j];
            uint2 r1 = arena[j + 1];
            atomicAdd(&s_acc[rep][r0.x & 0xFFu].x, __uint_as_float(r0.x & ~0xFFu));
            atomicAdd(&s_acc[rep][r0.x & 0xFFu].y, __uint_as_float(r0.y));
            atomicAdd(&s_acc[rep][r1.x & 0xFFu].x, __uint_as_float(r1.x & ~0xFFu));
            atomicAdd(&s_acc[rep][r1.x & 0xFFu].y, __uint_as_float(r1.y));
        }
        if (j < e) {
            uint2 rc = arena[j];
            atomicAdd(&s_acc[rep][rc.x & 0xFFu].x, __uint_as_float(rc.x & ~0xFFu));
            atomicAdd(&s_acc[rep][rc.x & 0xFFu].y, __uint_as_float(rc.y));
        }
    }
    __syncthreads();

    float v = 0.0f;
    int node = b * SPAN + (int)threadIdx.x;
    if (threadIdx.x < SPAN && node < N_NODES) {
        float2 S = make_float2(0.0f, 0.0f);
        #pragma unroll
        for (int rr = 0; rr < 4; ++rr) {
            float2 t = s_acc[rr][threadIdx.x];
            S.x += t.x; S.y += t.y;
        }
        float2 ui = u_tab[node];
        float2 bp = base_pq[node];
        float pc = ui.x * S.x - ui.y * S.y;   // Re(u*S)
        float qc = ui.x * S.y + ui.y * S.x;   // Im(u*S)
        float p = bp.x - pc, q = bp.y - qc;
        v = p * p + q * q;
    }
    #pragma unroll
    for (int off = 32; off > 0; off >>= 1) v += __shfl_down(v, off, 64);
    if ((threadIdx.x & 63) == 0) s_part[threadIdx.x >> 6] = v;
    __syncthreads();
    if (threadIdx.x == 0) {
        float t = 0.0f;
        #pragma unroll
        for (int w = 0; w < 16; ++w) t += s_part[w];
        atomicAdd(d_out, t * (1.0f / (float)N_NODES));
    }
}

// ---------------------------------------------------------------------------
extern "C" void kernel_launch(void* const* d_in, const int* in_sizes, int n_in,
                              void* d_out, int out_size, void* d_ws, size_t ws_size,
                              hipStream_t stream) {
    const float*  pred       = (const float*)d_in[0];
    const float*  target     = (const float*)d_in[1];
    const void*   edge_index = d_in[2];
    const float2* edge_attr  = (const float2*)d_in[3];
    const void*   mask       = d_in[4];
    float* out = (float*)d_out;

    char* ws = (char*)d_ws;
    float2*   u_tab   = (float2*)ws;                      // 800,000 B
    float2*   base_pq = (float2*)(ws + 800000);           // 800,000 B
    uint16_t* pref_T  = (uint16_t*)(ws + 1600000);        // 392*782*2 = 613,088 B
    uint2*    recs    = (uint2*)(ws + 2400000);           // 782*4096*8 = 25,624,576 B
                                                          // total ~28.0 MB

    prep_kernel<<<(N_NODES + 255) / 256, 256, 0, stream>>>(
        pred, target, mask, u_tab, base_pq, out, out_size);

    bin_kernel<<<NBLK, BTH, 0, stream>>>(
        edge_index, edge_attr, u_tab, recs, pref_T);

    reduce_kernel<<<NB, 1024, 0, stream>>>(
        recs, pref_T, u_tab, base_pq, out);
}